// Round 22
// baseline (3226.466 us; speedup 1.0000x reference)
//
#include <hip/hip_runtime.h>
#include <hip/hip_bf16.h>

#define NB   2048
#define NN0  111
#define NN1  56
#define NN2  28
#define FD   256
#define HD   128

// ---------------------------------------------------------------------------
// K1: stage-1 conv (R14 proven body) + abits dump.
// ---------------------------------------------------------------------------
__global__ __launch_bounds__(512, 2) void k_stage1(
    const float* __restrict__ x, const float* __restrict__ adj,
    const float* __restrict__ wg, const float* __restrict__ wsp,
    float* __restrict__ h1, unsigned* __restrict__ abg, int b0)
{
  extern __shared__ float sm[];
  float* xs   = sm;                                // 12432
  float* bufw = xs + 12432;                        // 112*128 (row 111 = 0)
  unsigned* abits = (unsigned*)(bufw + 14336);     // 448
  float* dis0 = (float*)(abits + 448);             // 112
  float* dis1 = dis0 + 112;                        // 112

  const int tid  = threadIdx.x;
  const int lane = tid & 63;
  const int wv   = tid >> 6;
  const int bl   = blockIdx.x;
  const int b    = b0 + bl;
  const float* xb = x   + (size_t)b * (NN0 * NN0);
  const float* ab = adj + (size_t)b * (NN0 * NN0);

  for (int idx = tid; idx < NN0 * NN0; idx += 512) {
    int i = idx / NN0, k = idx - i * NN0;
    xs[i * 112 + k] = xb[idx];
  }
  if (tid < 128) bufw[111 * 128 + tid] = 0.0f;
  if (tid >= 444 && tid < 448) abits[tid] = 0u;
  for (int i = wv; i < NN0; i += 8) {
    unsigned long long m0 = __ballot(ab[i * NN0 + lane] != 0.0f);
    float a1v = (64 + lane < NN0) ? ab[i * NN0 + 64 + lane] : 0.0f;
    unsigned long long m1 = __ballot(a1v != 0.0f);
    if (lane == 0) {
      abits[i * 4 + 0] = (unsigned)m0; abits[i * 4 + 1] = (unsigned)(m0 >> 32);
      abits[i * 4 + 2] = (unsigned)m1; abits[i * 4 + 3] = (unsigned)(m1 >> 32);
      int d = __popcll(m0) + __popcll(m1);
      dis0[i] = (d > 0) ? (1.0f / sqrtf((float)d)) : 0.0f;
      dis1[i] = 1.0f / sqrtf((float)(d + 1));
    }
  }
  __syncthreads();
  for (int q = tid; q < 448; q += 512) abg[(size_t)bl * 448 + q] = abits[q];

  // float2 neighbor sum; 4-way ILP; invalid -> zero row 111.
  // readfirstlane returns int -> truncate to unsigned BEFORE widening.
  auto nsum2 = [&](int i) {
    const unsigned* rb = abits + i * 4;
    unsigned lo0 = (unsigned)__builtin_amdgcn_readfirstlane(rb[0]);
    unsigned hi0 = (unsigned)__builtin_amdgcn_readfirstlane(rb[1]);
    unsigned lo1 = (unsigned)__builtin_amdgcn_readfirstlane(rb[2]);
    unsigned hi1 = (unsigned)__builtin_amdgcn_readfirstlane(rb[3]);
    unsigned long long u0 = ((unsigned long long)hi0 << 32) | (unsigned long long)lo0;
    unsigned long long u1 = ((unsigned long long)hi1 << 32) | (unsigned long long)lo1;
    float2 s0 = {0,0}, s1 = {0,0}, s2 = {0,0}, s3 = {0,0};
    while (u0 | u1) {
      int j0 = u0 ? (int)__builtin_ctzll(u0) : 111; u0 &= u0 - 1;
      int j1 = u0 ? (int)__builtin_ctzll(u0) : 111; u0 &= u0 - 1;
      int j2 = u1 ? (int)(64 + __builtin_ctzll(u1)) : 111; u1 &= u1 - 1;
      int j3 = u1 ? (int)(64 + __builtin_ctzll(u1)) : 111; u1 &= u1 - 1;
      float2 p0 = *(const float2*)&bufw[j0 * 128 + 2 * lane];
      float2 p1 = *(const float2*)&bufw[j1 * 128 + 2 * lane];
      float2 p2 = *(const float2*)&bufw[j2 * 128 + 2 * lane];
      float2 p3 = *(const float2*)&bufw[j3 * 128 + 2 * lane];
      s0.x += p0.x; s0.y += p0.y; s1.x += p1.x; s1.y += p1.y;
      s2.x += p2.x; s2.y += p2.y; s3.x += p3.x; s3.y += p3.y;
    }
    return make_float2((s0.x + s1.x) + (s2.x + s3.x),
                       (s0.y + s1.y) + (s2.y + s3.y));
  };

  float* h1b = h1 + (size_t)bl * (NN0 * FD);

  float aG0[14], aG1[14];
  float a2r[2][14], a1r[2][14], a0r[2][14];
#pragma unroll
  for (int t = 0; t < 14; ++t) {
    aG0[t] = 0.f; aG1[t] = 0.f;
    a2r[0][t] = 0.f; a2r[1][t] = 0.f;
    a1r[0][t] = 0.f; a1r[1][t] = 0.f;
    a0r[0][t] = 0.f; a0r[1][t] = 0.f;
  }
  {
    const float* pG = wg  + 2 * lane;
    const float* p2 = wsp + 2 * (NN0 * HD) + 2 * lane;
    const float* p1 = wsp + 1 * (NN0 * HD) + 2 * lane;
    const float* p0 = wsp + 2 * lane;
    for (int kq = 0; kq < 27; ++kq) {
      int k0 = kq * 4;
      float2 g[4], s2[4], u1w[4], v0[4];
#pragma unroll
      for (int j = 0; j < 4; ++j) {
        g[j]   = *(const float2*)&pG[(k0 + j) * HD];
        s2[j]  = *(const float2*)&p2[(k0 + j) * HD];
        u1w[j] = *(const float2*)&p1[(k0 + j) * HD];
        v0[j]  = *(const float2*)&p0[(k0 + j) * HD];
      }
#pragma unroll
      for (int t = 0; t < 14; ++t) {
        int r = wv + 8 * t;
        if (r < NN0) {
          float4 xq = *(const float4*)(xs + r * 112 + k0);
          aG0[t]    += xq.x*g[0].x   + xq.y*g[1].x   + xq.z*g[2].x   + xq.w*g[3].x;
          aG1[t]    += xq.x*g[0].y   + xq.y*g[1].y   + xq.z*g[2].y   + xq.w*g[3].y;
          a2r[0][t] += xq.x*s2[0].x  + xq.y*s2[1].x  + xq.z*s2[2].x  + xq.w*s2[3].x;
          a2r[1][t] += xq.x*s2[0].y  + xq.y*s2[1].y  + xq.z*s2[2].y  + xq.w*s2[3].y;
          a1r[0][t] += xq.x*u1w[0].x + xq.y*u1w[1].x + xq.z*u1w[2].x + xq.w*u1w[3].x;
          a1r[1][t] += xq.x*u1w[0].y + xq.y*u1w[1].y + xq.z*u1w[2].y + xq.w*u1w[3].y;
          a0r[0][t] += xq.x*v0[0].x  + xq.y*v0[1].x  + xq.z*v0[2].x  + xq.w*v0[3].x;
          a0r[1][t] += xq.x*v0[0].y  + xq.y*v0[1].y  + xq.z*v0[2].y  + xq.w*v0[3].y;
        }
      }
    }
#pragma unroll
    for (int k = 108; k < 111; ++k) {
      float2 gv = *(const float2*)&pG[k * HD];
      float2 sv = *(const float2*)&p2[k * HD];
      float2 uv = *(const float2*)&p1[k * HD];
      float2 vv = *(const float2*)&p0[k * HD];
#pragma unroll
      for (int t = 0; t < 14; ++t) {
        int r = wv + 8 * t;
        if (r < NN0) {
          float xv = xs[r * 112 + k];
          aG0[t]    += xv * gv.x; aG1[t]    += xv * gv.y;
          a2r[0][t] += xv * sv.x; a2r[1][t] += xv * sv.y;
          a1r[0][t] += xv * uv.x; a1r[1][t] += xv * uv.y;
          a0r[0][t] += xv * vv.x; a0r[1][t] += xv * vv.y;
        }
      }
    }
#pragma unroll
    for (int t = 0; t < 14; ++t) {
      int r = wv + 8 * t;
      if (r < NN0) {
        float d1 = dis1[r];
        *(float2*)&bufw[r * 128 + 2 * lane] = make_float2(d1 * aG0[t], d1 * aG1[t]);
      }
    }
  }
  __syncthreads();

  for (int t = 0; t < 14; ++t) {
    int i = wv + 8 * t;
    if (i < NN0) {
      float2 self = *(const float2*)&bufw[i * 128 + 2 * lane];
      float2 ns = nsum2(i);
      float d1 = dis1[i];
      float2 o = make_float2(fmaxf(d1 * (self.x + ns.x), 0.f),
                             fmaxf(d1 * (self.y + ns.y), 0.f));
      *(float2*)&h1b[i * FD + 2 * lane] = o;
    }
  }
  __syncthreads();
#pragma unroll
  for (int t = 0; t < 14; ++t) {
    int r = wv + 8 * t;
    if (r < NN0) {
      float d0r = dis0[r];
      *(float2*)&bufw[r * 128 + 2 * lane] = make_float2(d0r * a2r[0][t], d0r * a2r[1][t]);
    }
  }
  __syncthreads();
  float2 ur[14], cacc[14];
  for (int t = 0; t < 14; ++t) {
    int i = wv + 8 * t;
    if (i < NN0) {
      float2 ns = nsum2(i);
      float sc0 = -dis0[i] * dis0[i];
      ur[t] = make_float2(sc0 * ns.x, sc0 * ns.y);
      cacc[t] = make_float2(-a2r[0][t], -a2r[1][t]);
    } else { ur[t] = make_float2(0.f, 0.f); cacc[t] = make_float2(0.f, 0.f); }
  }
  __syncthreads();
#pragma unroll
  for (int t = 0; t < 14; ++t) {
    int r = wv + 8 * t;
    if (r < NN0) *(float2*)&bufw[r * 128 + 2 * lane] = ur[t];
  }
  __syncthreads();
  for (int t = 0; t < 14; ++t) {
    int i = wv + 8 * t;
    if (i < NN0) {
      float2 ns = nsum2(i);
      float d0i = dis0[i];
      cacc[t].x -= 2.0f * d0i * ns.x;
      cacc[t].y -= 2.0f * d0i * ns.y;
    }
  }
  __syncthreads();
#pragma unroll
  for (int t = 0; t < 14; ++t) {
    int r = wv + 8 * t;
    if (r < NN0) {
      float d0r = dis0[r];
      *(float2*)&bufw[r * 128 + 2 * lane] = make_float2(d0r * a1r[0][t], d0r * a1r[1][t]);
    }
  }
  __syncthreads();
  for (int t = 0; t < 14; ++t) {
    int i = wv + 8 * t;
    if (i < NN0) {
      float2 ns = nsum2(i);
      float d0i = dis0[i];
      float2 o = make_float2(fmaxf(cacc[t].x - d0i * ns.x + a0r[0][t], 0.f),
                             fmaxf(cacc[t].y - d0i * ns.y + a0r[1][t], 0.f));
      *(float2*)&h1b[i * FD + HD + 2 * lane] = o;
    }
  }
}

// ---------------------------------------------------------------------------
// K1b: pool1 scoring + selection + GATHER (R14 dataflow): writes hp1 so h1
// is fully consumed here; stage2 reads hp1 linearly.
// ---------------------------------------------------------------------------
__global__ __launch_bounds__(512) void k_sel(
    const float* __restrict__ h1, const unsigned* __restrict__ abg,
    float* __restrict__ hp1, unsigned long long* __restrict__ adjp)
{
  extern __shared__ float sm[];
  float* bufw = sm;                                // 112*128 (row 111 = 0)
  unsigned* abits = (unsigned*)(bufw + 14336);     // 448
  float* dinv = (float*)(abits + 448);             // 112
  float* sc   = dinv + 112;                        // 112
  int*   sel  = (int*)(sc + 112);                  // 64

  const int tid = threadIdx.x, lane = tid & 63, wv = tid >> 6;
  const int bl = blockIdx.x;
  const float* h1b = h1 + (size_t)bl * (NN0 * FD);

  for (int q = tid; q < 448; q += 512) abits[q] = abg[(size_t)bl * 448 + q];
  if (tid < 128) bufw[111 * 128 + tid] = 0.0f;
  __syncthreads();
  if (tid < NN0) {
    int d = __popc(abits[tid*4]) + __popc(abits[tid*4+1])
          + __popc(abits[tid*4+2]) + __popc(abits[tid*4+3]);
    dinv[tid] = (d > 0) ? (1.0f / (float)d) : 0.0f;
  }

  auto nsum2 = [&](int i) {
    const unsigned* rb = abits + i * 4;
    unsigned lo0 = (unsigned)__builtin_amdgcn_readfirstlane(rb[0]);
    unsigned hi0 = (unsigned)__builtin_amdgcn_readfirstlane(rb[1]);
    unsigned lo1 = (unsigned)__builtin_amdgcn_readfirstlane(rb[2]);
    unsigned hi1 = (unsigned)__builtin_amdgcn_readfirstlane(rb[3]);
    unsigned long long u0 = ((unsigned long long)hi0 << 32) | (unsigned long long)lo0;
    unsigned long long u1 = ((unsigned long long)hi1 << 32) | (unsigned long long)lo1;
    float2 s0 = {0,0}, s1 = {0,0}, s2 = {0,0}, s3 = {0,0};
    while (u0 | u1) {
      int j0 = u0 ? (int)__builtin_ctzll(u0) : 111; u0 &= u0 - 1;
      int j1 = u0 ? (int)__builtin_ctzll(u0) : 111; u0 &= u0 - 1;
      int j2 = u1 ? (int)(64 + __builtin_ctzll(u1)) : 111; u1 &= u1 - 1;
      int j3 = u1 ? (int)(64 + __builtin_ctzll(u1)) : 111; u1 &= u1 - 1;
      float2 p0 = *(const float2*)&bufw[j0 * 128 + 2 * lane];
      float2 p1 = *(const float2*)&bufw[j1 * 128 + 2 * lane];
      float2 p2 = *(const float2*)&bufw[j2 * 128 + 2 * lane];
      float2 p3 = *(const float2*)&bufw[j3 * 128 + 2 * lane];
      s0.x += p0.x; s0.y += p0.y; s1.x += p1.x; s1.y += p1.y;
      s2.x += p2.x; s2.y += p2.y; s3.x += p3.x; s3.y += p3.y;
    }
    return make_float2((s0.x + s1.x) + (s2.x + s3.x),
                       (s0.y + s1.y) + (s2.y + s3.y));
  };

#pragma unroll
  for (int t = 0; t < 14; ++t) {
    int r = wv + 8 * t;
    if (r < NN0)
      *(float2*)&bufw[r * 128 + 2 * lane] = *(const float2*)&h1b[r * FD + 2 * lane];
  }
  __syncthreads();
  float sA[14];
  for (int t = 0; t < 14; ++t) {
    int i = wv + 8 * t;
    if (i < NN0) {
      float2 self = *(const float2*)&bufw[i * 128 + 2 * lane];
      float2 nb = nsum2(i);
      float di = dinv[i];
      sA[t] = fabsf(self.x - di * nb.x) + fabsf(self.y - di * nb.y);
    } else sA[t] = 0.f;
  }
  __syncthreads();
#pragma unroll
  for (int t = 0; t < 14; ++t) {
    int r = wv + 8 * t;
    if (r < NN0)
      *(float2*)&bufw[r * 128 + 2 * lane] = *(const float2*)&h1b[r * FD + HD + 2 * lane];
  }
  __syncthreads();
  for (int t = 0; t < 14; ++t) {
    int i = wv + 8 * t;
    if (i < NN0) {
      float2 self = *(const float2*)&bufw[i * 128 + 2 * lane];
      float2 nb = nsum2(i);
      float di = dinv[i];
      float s = sA[t] + fabsf(self.x - di * nb.x) + fabsf(self.y - di * nb.y);
      for (int off = 32; off; off >>= 1) s += __shfl_xor(s, off);
      if (lane == 0) sc[i] = s;
    }
  }
  __syncthreads();
  if (tid < NN0) {
    float my = sc[tid];
    int cnt = 0;
    for (int j = 0; j < NN0; ++j) {
      float sj = sc[j];
      cnt += (sj > my) || (sj == my && j < tid);
    }
    if (cnt < NN1) sel[cnt] = tid;
  }
  __syncthreads();
  // adjp + gather hp1 = h1[sel] (h1 fully consumed here)
  float* hpb = hp1 + (size_t)bl * (NN1 * FD);
  for (int r = wv; r < NN1; r += 8) {
    int i = sel[r];
    const float* hr = h1b + (size_t)i * FD + lane;
    float* dst = hpb + (size_t)r * FD + lane;
    dst[0] = hr[0]; dst[64] = hr[64]; dst[128] = hr[128]; dst[192] = hr[192];
    int j2 = (lane < NN1) ? sel[lane] : 0;
    bool bit = (lane < NN1) && ((abits[i * 4 + (j2 >> 5)] >> (j2 & 31)) & 1);
    unsigned long long m = __ballot(bit);
    if (lane == 0) adjp[(size_t)bl * NN1 + r] = m;
  }
}

// ---------------------------------------------------------------------------
// K2: stage-2 conv FUSED with pool2 + x1/x2 readouts; reads hp1 LINEARLY.
// ---------------------------------------------------------------------------
__global__ __launch_bounds__(512, 2) void k_stage2(
    const float* __restrict__ hp1,
    const unsigned long long* __restrict__ adjp,
    const float* __restrict__ wg, const float* __restrict__ wsp,
    float* __restrict__ zbuf)
{
  extern __shared__ float sm[];
  float* hs   = sm;                                // 57*256 (row 56 = 0)
  float* bufw = hs + 14592;                        // 57*128 (row 56 = 0)
  unsigned long long* rowm = (unsigned long long*)(bufw + 7296); // 56 u64
  float* dis0 = (float*)(rowm + 56);               // 64
  float* dis1 = dis0 + 64;                         // 64
  float* dinv = dis1 + 64;                         // 64
  float* sc   = dinv + 64;                         // 64
  int* sel2   = (int*)(sc + 64);                   // 32+pad

  const int tid = threadIdx.x, lane = tid & 63, wv = tid >> 6;
  const int bl = blockIdx.x;
  const float* hp1b = hp1 + (size_t)bl * (NN1 * FD);
  float* zb = zbuf + (size_t)bl * 8192;

  if (tid < 128) bufw[56 * 128 + tid] = 0.0f;
  if (tid < 256) hs[56 * 256 + tid] = 0.0f;
  if (tid < NN1) {
    unsigned long long m = adjp[(size_t)bl * NN1 + tid];
    rowm[tid] = m;
    int d = __popcll(m);
    dis0[tid] = (d > 0) ? (1.0f / sqrtf((float)d)) : 0.0f;
    dis1[tid] = 1.0f / sqrtf((float)(d + 1));
    dinv[tid] = (d > 0) ? (1.0f / (float)d) : 0.0f;
  }
  __syncthreads();
  for (int q = tid; q < NN1 * 64; q += 512)
    ((float4*)hs)[q] = ((const float4*)hp1b)[q];
  __syncthreads();
  if (tid < FD) {
    float mx = -3.402823466e38f, sm2 = 0.0f;
    for (int r = 0; r < NN1; ++r) {
      float v = hs[r * 256 + tid];
      mx = fmaxf(mx, v); sm2 += v;
    }
    zb[7168 + tid] = mx;
    zb[7424 + tid] = sm2 / 56.0f;
  }

  auto nsum2 = [&](int i) {
    unsigned long long m = rowm[i];
    unsigned lo = (unsigned)__builtin_amdgcn_readfirstlane((unsigned)m);
    unsigned hi = (unsigned)__builtin_amdgcn_readfirstlane((unsigned)(m >> 32));
    unsigned long long u = ((unsigned long long)hi << 32) | (unsigned long long)lo;
    float2 s0 = {0,0}, s1 = {0,0}, s2 = {0,0}, s3 = {0,0};
    while (u) {
      int j0 = (int)__builtin_ctzll(u); u &= u - 1;
      int j1 = u ? (int)__builtin_ctzll(u) : 56; u &= u - 1;
      int j2 = u ? (int)__builtin_ctzll(u) : 56; u &= u - 1;
      int j3 = u ? (int)__builtin_ctzll(u) : 56; u &= u - 1;
      float2 p0 = *(const float2*)&bufw[j0 * 128 + 2 * lane];
      float2 p1 = *(const float2*)&bufw[j1 * 128 + 2 * lane];
      float2 p2 = *(const float2*)&bufw[j2 * 128 + 2 * lane];
      float2 p3 = *(const float2*)&bufw[j3 * 128 + 2 * lane];
      s0.x += p0.x; s0.y += p0.y; s1.x += p1.x; s1.y += p1.y;
      s2.x += p2.x; s2.y += p2.y; s3.x += p3.x; s3.y += p3.y;
    }
    return make_float2((s0.x + s1.x) + (s2.x + s3.x),
                       (s0.y + s1.y) + (s2.y + s3.y));
  };
  auto nsum_hs = [&](int i, int base) {
    unsigned long long m = rowm[i];
    unsigned lo = (unsigned)__builtin_amdgcn_readfirstlane((unsigned)m);
    unsigned hi = (unsigned)__builtin_amdgcn_readfirstlane((unsigned)(m >> 32));
    unsigned long long u = ((unsigned long long)hi << 32) | (unsigned long long)lo;
    float2 s0 = {0,0}, s1 = {0,0}, s2 = {0,0}, s3 = {0,0};
    while (u) {
      int j0 = (int)__builtin_ctzll(u); u &= u - 1;
      int j1 = u ? (int)__builtin_ctzll(u) : 56; u &= u - 1;
      int j2 = u ? (int)__builtin_ctzll(u) : 56; u &= u - 1;
      int j3 = u ? (int)__builtin_ctzll(u) : 56; u &= u - 1;
      float2 p0 = *(const float2*)&hs[j0 * 256 + base + 2 * lane];
      float2 p1 = *(const float2*)&hs[j1 * 256 + base + 2 * lane];
      float2 p2 = *(const float2*)&hs[j2 * 256 + base + 2 * lane];
      float2 p3 = *(const float2*)&hs[j3 * 256 + base + 2 * lane];
      s0.x += p0.x; s0.y += p0.y; s1.x += p1.x; s1.y += p1.y;
      s2.x += p2.x; s2.y += p2.y; s3.x += p3.x; s3.y += p3.y;
    }
    return make_float2((s0.x + s1.x) + (s2.x + s3.x),
                       (s0.y + s1.y) + (s2.y + s3.y));
  };

  float aG0[7], aG1[7];
  float a2r[2][7], a1r[2][7], a0r[2][7];
#pragma unroll
  for (int t = 0; t < 7; ++t) {
    aG0[t] = 0.f; aG1[t] = 0.f;
    a2r[0][t] = 0.f; a2r[1][t] = 0.f;
    a1r[0][t] = 0.f; a1r[1][t] = 0.f;
    a0r[0][t] = 0.f; a0r[1][t] = 0.f;
  }
  {
    const float* pG = wg  + 2 * lane;
    const float* p2 = wsp + 2 * (FD * HD) + 2 * lane;
    const float* p1 = wsp + 1 * (FD * HD) + 2 * lane;
    const float* p0 = wsp + 2 * lane;
    for (int kq = 0; kq < 64; ++kq) {
      int k0 = kq * 4;
      float2 g[4], s2[4], u1w[4], v0[4];
#pragma unroll
      for (int j = 0; j < 4; ++j) {
        g[j]   = *(const float2*)&pG[(k0 + j) * HD];
        s2[j]  = *(const float2*)&p2[(k0 + j) * HD];
        u1w[j] = *(const float2*)&p1[(k0 + j) * HD];
        v0[j]  = *(const float2*)&p0[(k0 + j) * HD];
      }
#pragma unroll
      for (int t = 0; t < 7; ++t) {
        int r = wv + 8 * t;
        float4 xq = *(const float4*)(hs + r * 256 + k0);
        aG0[t]    += xq.x*g[0].x   + xq.y*g[1].x   + xq.z*g[2].x   + xq.w*g[3].x;
        aG1[t]    += xq.x*g[0].y   + xq.y*g[1].y   + xq.z*g[2].y   + xq.w*g[3].y;
        a2r[0][t] += xq.x*s2[0].x  + xq.y*s2[1].x  + xq.z*s2[2].x  + xq.w*s2[3].x;
        a2r[1][t] += xq.x*s2[0].y  + xq.y*s2[1].y  + xq.z*s2[2].y  + xq.w*s2[3].y;
        a1r[0][t] += xq.x*u1w[0].x + xq.y*u1w[1].x + xq.z*u1w[2].x + xq.w*u1w[3].x;
        a1r[1][t] += xq.x*u1w[0].y + xq.y*u1w[1].y + xq.z*u1w[2].y + xq.w*u1w[3].y;
        a0r[0][t] += xq.x*v0[0].x  + xq.y*v0[1].x  + xq.z*v0[2].x  + xq.w*v0[3].x;
        a0r[1][t] += xq.x*v0[0].y  + xq.y*v0[1].y  + xq.z*v0[2].y  + xq.w*v0[3].y;
      }
    }
#pragma unroll
    for (int t = 0; t < 7; ++t) {
      int r = wv + 8 * t;
      float d1 = dis1[r];
      *(float2*)&bufw[r * 128 + 2 * lane] = make_float2(d1 * aG0[t], d1 * aG1[t]);
    }
  }
  __syncthreads();
  float2 ho[7];
#pragma unroll
  for (int t = 0; t < 7; ++t) {
    int i = wv + 8 * t;
    float2 self = *(const float2*)&bufw[i * 128 + 2 * lane];
    float2 ns = nsum2(i);
    float d1 = dis1[i];
    float2 o = make_float2(fmaxf(d1 * (self.x + ns.x), 0.f),
                           fmaxf(d1 * (self.y + ns.y), 0.f));
    *(float2*)&hs[i * 256 + 2 * lane] = o;
    ho[t] = o;
  }
  __syncthreads();
  float sA[7];
#pragma unroll
  for (int t = 0; t < 7; ++t) {
    int i = wv + 8 * t;
    float2 nb = nsum_hs(i, 0);
    float di = dinv[i];
    sA[t] = fabsf(ho[t].x - di * nb.x) + fabsf(ho[t].y - di * nb.y);
  }
#pragma unroll
  for (int t = 0; t < 7; ++t) {
    int r = wv + 8 * t;
    float d0r = dis0[r];
    *(float2*)&bufw[r * 128 + 2 * lane] = make_float2(d0r * a2r[0][t], d0r * a2r[1][t]);
  }
  __syncthreads();
  float2 ur[7], cacc[7];
#pragma unroll
  for (int t = 0; t < 7; ++t) {
    int i = wv + 8 * t;
    float2 ns = nsum2(i);
    float sc0 = -dis0[i] * dis0[i];
    ur[t] = make_float2(sc0 * ns.x, sc0 * ns.y);
    cacc[t] = make_float2(-a2r[0][t], -a2r[1][t]);
  }
  __syncthreads();
#pragma unroll
  for (int t = 0; t < 7; ++t) {
    int r = wv + 8 * t;
    *(float2*)&bufw[r * 128 + 2 * lane] = ur[t];
  }
  __syncthreads();
#pragma unroll
  for (int t = 0; t < 7; ++t) {
    int i = wv + 8 * t;
    float2 ns = nsum2(i);
    float d0i = dis0[i];
    cacc[t].x -= 2.0f * d0i * ns.x;
    cacc[t].y -= 2.0f * d0i * ns.y;
  }
  __syncthreads();
#pragma unroll
  for (int t = 0; t < 7; ++t) {
    int r = wv + 8 * t;
    float d0r = dis0[r];
    *(float2*)&bufw[r * 128 + 2 * lane] = make_float2(d0r * a1r[0][t], d0r * a1r[1][t]);
  }
  __syncthreads();
#pragma unroll
  for (int t = 0; t < 7; ++t) {
    int i = wv + 8 * t;
    float2 ns = nsum2(i);
    float d0i = dis0[i];
    float2 o = make_float2(fmaxf(cacc[t].x - d0i * ns.x + a0r[0][t], 0.f),
                           fmaxf(cacc[t].y - d0i * ns.y + a0r[1][t], 0.f));
    *(float2*)&hs[i * 256 + 128 + 2 * lane] = o;
    cacc[t] = o;
  }
  __syncthreads();
#pragma unroll
  for (int t = 0; t < 7; ++t) {
    int i = wv + 8 * t;
    float2 nb = nsum_hs(i, 128);
    float di = dinv[i];
    float s = sA[t] + fabsf(cacc[t].x - di * nb.x) + fabsf(cacc[t].y - di * nb.y);
    for (int off = 32; off; off >>= 1) s += __shfl_xor(s, off);
    if (lane == 0) sc[i] = s;
  }
  __syncthreads();
  if (tid < NN1) {
    float my = sc[tid];
    int cnt = 0;
    for (int j = 0; j < NN1; ++j) {
      float sj = sc[j];
      cnt += (sj > my) || (sj == my && j < tid);
    }
    if (cnt < NN2) sel2[cnt] = tid;
  }
  __syncthreads();
  for (int r = wv; r < NN2; r += 8) {
    const float* hr = hs + sel2[r] * 256 + lane;
    float* dst = zb + r * 256 + lane;
    dst[0] = hr[0]; dst[64] = hr[64]; dst[128] = hr[128]; dst[192] = hr[192];
  }
  if (tid < FD) {
    float mx = -3.402823466e38f, sm2 = 0.0f;
    for (int r = 0; r < NN2; ++r) {
      float v = hs[sel2[r] * 256 + tid];
      mx = fmaxf(mx, v); sm2 += v;
    }
    zb[7680 + tid] = mx;
    zb[7936 + tid] = sm2 / 28.0f;
  }
}

// ---------------------------------------------------------------------------
// K5a: lin1 split-K partial. grid (G/8, 4): blockIdx.y = K-quarter (2048).
// ---------------------------------------------------------------------------
__global__ __launch_bounds__(512) void k_lin1p(
    const float* __restrict__ zbuf, const float* __restrict__ w,
    float* __restrict__ part, int G)
{
  __shared__ float smem[8576];           // wt: 32*260=8320 | zt: 32*8=256
  float* wt = smem;
  float* zt = smem + 8320;

  const int tid = threadIdx.x;
  const int col = tid & 63;
  const int ksub = tid >> 6;             // 0..7
  const int g0 = blockIdx.x * 8;
  const int kq4 = blockIdx.y;            // K-quarter
  const int kbase = kq4 * 2048;
  const int gz = tid >> 5, kz = tid & 31;

  float acc[8][4];
#pragma unroll
  for (int g = 0; g < 8; ++g)
#pragma unroll
    for (int c = 0; c < 4; ++c) acc[g][c] = 0.f;

  const float* wbase = w + (size_t)(kbase + ksub) * 256 + col * 4;
  const float* zbase = zbuf + (size_t)(g0 + gz) * 8192 + kbase + kz;

  float4 wr4[4]; float zr1 = 0.f;
#pragma unroll
  for (int q = 0; q < 4; ++q)
    wr4[q] = *(const float4*)(wbase + (size_t)(8 * q) * 256);
  if (tid < 256) zr1 = zbase[0];
#pragma unroll
  for (int q = 0; q < 4; ++q)
    *(float4*)&wt[(ksub + 8 * q) * 260 + col * 4] = wr4[q];
  if (tid < 256) zt[kz * 8 + gz] = zr1;
  __syncthreads();

  for (int it = 0; it < 64; ++it) {
    if (it + 1 < 64) {
      const float* wn = wbase + (size_t)(it + 1) * 32 * 256;
#pragma unroll
      for (int q = 0; q < 4; ++q)
        wr4[q] = *(const float4*)(wn + (size_t)(8 * q) * 256);
      if (tid < 256) zr1 = zbase[(it + 1) * 32];
    }
#pragma unroll
    for (int kk = 0; kk < 4; ++kk) {
      int k = ksub * 4 + kk;
      float4 za = *(const float4*)&zt[k * 8];
      float4 zb = *(const float4*)&zt[k * 8 + 4];
      float4 wv = *(const float4*)&wt[k * 260 + col * 4];
      acc[0][0] += za.x * wv.x; acc[0][1] += za.x * wv.y; acc[0][2] += za.x * wv.z; acc[0][3] += za.x * wv.w;
      acc[1][0] += za.y * wv.x; acc[1][1] += za.y * wv.y; acc[1][2] += za.y * wv.z; acc[1][3] += za.y * wv.w;
      acc[2][0] += za.z * wv.x; acc[2][1] += za.z * wv.y; acc[2][2] += za.z * wv.z; acc[2][3] += za.z * wv.w;
      acc[3][0] += za.w * wv.x; acc[3][1] += za.w * wv.y; acc[3][2] += za.w * wv.z; acc[3][3] += za.w * wv.w;
      acc[4][0] += zb.x * wv.x; acc[4][1] += zb.x * wv.y; acc[4][2] += zb.x * wv.z; acc[4][3] += zb.x * wv.w;
      acc[5][0] += zb.y * wv.x; acc[5][1] += zb.y * wv.y; acc[5][2] += zb.y * wv.z; acc[5][3] += zb.y * wv.w;
      acc[6][0] += zb.z * wv.x; acc[6][1] += zb.z * wv.y; acc[6][2] += zb.z * wv.z; acc[6][3] += zb.z * wv.w;
      acc[7][0] += zb.w * wv.x; acc[7][1] += zb.w * wv.y; acc[7][2] += zb.w * wv.z; acc[7][3] += zb.w * wv.w;
    }
    __syncthreads();
    if (it + 1 < 64) {
#pragma unroll
      for (int q = 0; q < 4; ++q)
        *(float4*)&wt[(ksub + 8 * q) * 260 + col * 4] = wr4[q];
      if (tid < 256) zt[kz * 8 + gz] = zr1;
      __syncthreads();
    }
  }

  float* red = smem;
  for (int half = 4; half >= 1; half >>= 1) {
    if (ksub >= half && ksub < 2 * half) {
      float* dst = red + ((ksub - half) * 64 + col) * 33;
#pragma unroll
      for (int g = 0; g < 8; ++g)
#pragma unroll
        for (int c = 0; c < 4; ++c) dst[g * 4 + c] = acc[g][c];
    }
    __syncthreads();
    if (ksub < half) {
      const float* src = red + (ksub * 64 + col) * 33;
#pragma unroll
      for (int g = 0; g < 8; ++g)
#pragma unroll
        for (int c = 0; c < 4; ++c) acc[g][c] += src[g * 4 + c];
    }
    __syncthreads();
  }
  if (ksub == 0) {
    float* pb = part + ((size_t)kq4 * G + g0) * 256;
#pragma unroll
    for (int g = 0; g < 8; ++g) {
      float4 v = make_float4(acc[g][0], acc[g][1], acc[g][2], acc[g][3]);
      *(float4*)&pb[(size_t)g * 256 + col * 4] = v;
    }
  }
}

// ---------------------------------------------------------------------------
// K5b: reduce 4 K-quarter partials + bias + relu -> fbuf. Fixed order.
// ---------------------------------------------------------------------------
__global__ __launch_bounds__(256) void k_lin1r(
    const float* __restrict__ part, const float* __restrict__ bias,
    float* __restrict__ fbuf, int G)
{
  int idx = blockIdx.x * 256 + threadIdx.x;   // float4 index over G*64
  int c4 = idx & 63, g = idx >> 6;
  size_t stride = (size_t)G * 256;
  const float* p = part + (size_t)g * 256 + c4 * 4;
  float4 s = *(const float4*)p;
#pragma unroll
  for (int q = 1; q < 4; ++q) {
    float4 v = *(const float4*)(p + (size_t)q * stride);
    s.x += v.x; s.y += v.y; s.z += v.z; s.w += v.w;
  }
  float4 bv = *(const float4*)(bias + c4 * 4);
  s.x = fmaxf(s.x + bv.x, 0.f); s.y = fmaxf(s.y + bv.y, 0.f);
  s.z = fmaxf(s.z + bv.z, 0.f); s.w = fmaxf(s.w + bv.w, 0.f);
  *(float4*)(fbuf + (size_t)g * 256 + c4 * 4) = s;
}

// ---------------------------------------------------------------------------
// K6: features = relu(f @ lin2_w + b2); x_lo = softmax(features)
// ---------------------------------------------------------------------------
__global__ __launch_bounds__(128) void k_head(
    const float* __restrict__ fbuf, const float* __restrict__ w2,
    const float* __restrict__ b2, float* __restrict__ out, int b0)
{
  __shared__ __align__(16) float fs[256];
  __shared__ float red[2];
  const int tid = threadIdx.x, lane = tid & 63, wv = tid >> 6;
  const int bl = blockIdx.x, b = b0 + bl;
  for (int i = tid; i < 256; i += 128) fs[i] = fbuf[(size_t)bl * 256 + i];
  __syncthreads();
  float acc = b2[tid];
  for (int k = 0; k < 256; k += 4) {
    float4 fq = *(const float4*)(fs + k);
    acc += fq.x * w2[(k + 0) * 128 + tid] + fq.y * w2[(k + 1) * 128 + tid]
         + fq.z * w2[(k + 2) * 128 + tid] + fq.w * w2[(k + 3) * 128 + tid];
  }
  float feat = fmaxf(acc, 0.0f);
  out[(size_t)(NB * 128) + (size_t)b * 128 + tid] = feat;
  float m = feat;
  for (int off = 32; off; off >>= 1) m = fmaxf(m, __shfl_xor(m, off));
  if (lane == 0) red[wv] = m;
  __syncthreads();
  m = fmaxf(red[0], red[1]);
  float e = expf(feat - m);
  float s = e;
  for (int off = 32; off; off >>= 1) s += __shfl_xor(s, off);
  __syncthreads();
  if (lane == 0) red[wv] = s;
  __syncthreads();
  s = red[0] + red[1];
  out[(size_t)b * 128 + tid] = e / s;
}

// ---------------------------------------------------------------------------
extern "C" void kernel_launch(void* const* d_in, const int* in_sizes, int n_in,
                              void* d_out, int out_size, void* d_ws, size_t ws_size,
                              hipStream_t stream) {
  const float* x    = (const float*)d_in[0];
  const float* adj  = (const float*)d_in[1];
  const float* wg1  = (const float*)d_in[2];
  const float* wsp1 = (const float*)d_in[3];
  const float* wg2  = (const float*)d_in[4];
  const float* wsp2 = (const float*)d_in[5];
  const float* l1w  = (const float*)d_in[6];
  const float* l1b  = (const float*)d_in[7];
  const float* l2w  = (const float*)d_in[8];
  const float* l2b  = (const float*)d_in[9];
  float* out = (float*)d_out;

  auto al = [](size_t v) { return (v + 255) & ~(size_t)255; };
  size_t oh1, oabg, ohp1, oadjp, oz, opart, of;
  auto plan = [&](int g) -> size_t {
    size_t o = 0;
    oh1 = o;   o += al((size_t)g * NN0 * FD * 4);
    oabg = o;  o += al((size_t)g * 448 * 4);
    ohp1 = o;  o += al((size_t)g * NN1 * FD * 4);
    oadjp = o; o += al((size_t)g * NN1 * 8);
    oz = o;    o += al((size_t)g * 8192 * 4);
    opart = o; o += al((size_t)g * 256 * 4 * 4);
    of = o;    o += al((size_t)g * FD * 4);
    return o;
  };
  int G = 2048;
  while (G > 64 && plan(G) > ws_size) G >>= 1;
  if (plan(G) > ws_size) return;

  char* wsb = (char*)d_ws;
  float* h1  = (float*)(wsb + oh1);
  unsigned* abg = (unsigned*)(wsb + oabg);
  float* hp1 = (float*)(wsb + ohp1);
  unsigned long long* adjp = (unsigned long long*)(wsb + oadjp);
  float* zbuf = (float*)(wsb + oz);
  float* part = (float*)(wsb + opart);
  float* fbuf = (float*)(wsb + of);

  const size_t LDS1 = (size_t)(12432 + 14336 + 448 + 112 + 112) * 4;            // 109,760
  const size_t LDSS = (size_t)(14336 + 448 + 112 + 112 + 64) * 4;               // 60,288
  const size_t LDS2 = (size_t)(14592 + 7296 + 112 + 64 + 64 + 64 + 64 + 64) * 4; // 89,280

  for (int b0 = 0; b0 < NB; b0 += G) {
    k_stage1<<<G, 512, LDS1, stream>>>(x, adj, wg1, wsp1, h1, abg, b0);
    k_sel<<<G, 512, LDSS, stream>>>(h1, abg, hp1, adjp);
    k_stage2<<<G, 512, LDS2, stream>>>(hp1, adjp, wg2, wsp2, zbuf);
    k_lin1p<<<dim3(G / 8, 4), 512, 0, stream>>>(zbuf, l1w, part, G);
    k_lin1r<<<G / 4, 256, 0, stream>>>(part, l1b, fbuf, G);
    k_head<<<G, 128, 0, stream>>>(fbuf, l2w, l2b, out, b0);
  }
}

// Round 23
// 3084.731 us; speedup vs baseline: 1.0459x; 1.0459x over previous
//
#include <hip/hip_runtime.h>
#include <hip/hip_bf16.h>

#define NB   2048
#define NN0  111
#define NN1  56
#define NN2  28
#define FD   256
#define HD   128

// ---------------------------------------------------------------------------
// K1: stage-1 conv (R14 proven body) + abits dump for downstream kernels.
// ---------------------------------------------------------------------------
__global__ __launch_bounds__(512, 2) void k_stage1(
    const float* __restrict__ x, const float* __restrict__ adj,
    const float* __restrict__ wg, const float* __restrict__ wsp,
    float* __restrict__ h1, unsigned* __restrict__ abg, int b0)
{
  extern __shared__ float sm[];
  float* xs   = sm;                                // 12432
  float* bufw = xs + 12432;                        // 112*128 (row 111 = 0)
  unsigned* abits = (unsigned*)(bufw + 14336);     // 448
  float* dis0 = (float*)(abits + 448);             // 112
  float* dis1 = dis0 + 112;                        // 112

  const int tid  = threadIdx.x;
  const int lane = tid & 63;
  const int wv   = tid >> 6;
  const int bl   = blockIdx.x;
  const int b    = b0 + bl;
  const float* xb = x   + (size_t)b * (NN0 * NN0);
  const float* ab = adj + (size_t)b * (NN0 * NN0);

  for (int idx = tid; idx < NN0 * NN0; idx += 512) {
    int i = idx / NN0, k = idx - i * NN0;
    xs[i * 112 + k] = xb[idx];
  }
  if (tid < 128) bufw[111 * 128 + tid] = 0.0f;
  if (tid >= 444 && tid < 448) abits[tid] = 0u;
  for (int i = wv; i < NN0; i += 8) {
    unsigned long long m0 = __ballot(ab[i * NN0 + lane] != 0.0f);
    float a1v = (64 + lane < NN0) ? ab[i * NN0 + 64 + lane] : 0.0f;
    unsigned long long m1 = __ballot(a1v != 0.0f);
    if (lane == 0) {
      abits[i * 4 + 0] = (unsigned)m0; abits[i * 4 + 1] = (unsigned)(m0 >> 32);
      abits[i * 4 + 2] = (unsigned)m1; abits[i * 4 + 3] = (unsigned)(m1 >> 32);
      int d = __popcll(m0) + __popcll(m1);
      dis0[i] = (d > 0) ? (1.0f / sqrtf((float)d)) : 0.0f;
      dis1[i] = 1.0f / sqrtf((float)(d + 1));
    }
  }
  __syncthreads();
  for (int q = tid; q < 448; q += 512) abg[(size_t)bl * 448 + q] = abits[q];

  // float2 neighbor sum; 4-way ILP; invalid -> zero row 111.
  // readfirstlane returns int -> truncate to unsigned BEFORE widening.
  auto nsum2 = [&](int i) {
    const unsigned* rb = abits + i * 4;
    unsigned lo0 = (unsigned)__builtin_amdgcn_readfirstlane(rb[0]);
    unsigned hi0 = (unsigned)__builtin_amdgcn_readfirstlane(rb[1]);
    unsigned lo1 = (unsigned)__builtin_amdgcn_readfirstlane(rb[2]);
    unsigned hi1 = (unsigned)__builtin_amdgcn_readfirstlane(rb[3]);
    unsigned long long u0 = ((unsigned long long)hi0 << 32) | (unsigned long long)lo0;
    unsigned long long u1 = ((unsigned long long)hi1 << 32) | (unsigned long long)lo1;
    float2 s0 = {0,0}, s1 = {0,0}, s2 = {0,0}, s3 = {0,0};
    while (u0 | u1) {
      int j0 = u0 ? (int)__builtin_ctzll(u0) : 111; u0 &= u0 - 1;
      int j1 = u0 ? (int)__builtin_ctzll(u0) : 111; u0 &= u0 - 1;
      int j2 = u1 ? (int)(64 + __builtin_ctzll(u1)) : 111; u1 &= u1 - 1;
      int j3 = u1 ? (int)(64 + __builtin_ctzll(u1)) : 111; u1 &= u1 - 1;
      float2 p0 = *(const float2*)&bufw[j0 * 128 + 2 * lane];
      float2 p1 = *(const float2*)&bufw[j1 * 128 + 2 * lane];
      float2 p2 = *(const float2*)&bufw[j2 * 128 + 2 * lane];
      float2 p3 = *(const float2*)&bufw[j3 * 128 + 2 * lane];
      s0.x += p0.x; s0.y += p0.y; s1.x += p1.x; s1.y += p1.y;
      s2.x += p2.x; s2.y += p2.y; s3.x += p3.x; s3.y += p3.y;
    }
    return make_float2((s0.x + s1.x) + (s2.x + s3.x),
                       (s0.y + s1.y) + (s2.y + s3.y));
  };

  float* h1b = h1 + (size_t)bl * (NN0 * FD);

  float aG0[14], aG1[14];
  float a2r[2][14], a1r[2][14], a0r[2][14];
#pragma unroll
  for (int t = 0; t < 14; ++t) {
    aG0[t] = 0.f; aG1[t] = 0.f;
    a2r[0][t] = 0.f; a2r[1][t] = 0.f;
    a1r[0][t] = 0.f; a1r[1][t] = 0.f;
    a0r[0][t] = 0.f; a0r[1][t] = 0.f;
  }
  {
    const float* pG = wg  + 2 * lane;
    const float* p2 = wsp + 2 * (NN0 * HD) + 2 * lane;
    const float* p1 = wsp + 1 * (NN0 * HD) + 2 * lane;
    const float* p0 = wsp + 2 * lane;
    for (int kq = 0; kq < 27; ++kq) {
      int k0 = kq * 4;
      float2 g[4], s2[4], u1w[4], v0[4];
#pragma unroll
      for (int j = 0; j < 4; ++j) {
        g[j]   = *(const float2*)&pG[(k0 + j) * HD];
        s2[j]  = *(const float2*)&p2[(k0 + j) * HD];
        u1w[j] = *(const float2*)&p1[(k0 + j) * HD];
        v0[j]  = *(const float2*)&p0[(k0 + j) * HD];
      }
#pragma unroll
      for (int t = 0; t < 14; ++t) {
        int r = wv + 8 * t;
        if (r < NN0) {
          float4 xq = *(const float4*)(xs + r * 112 + k0);
          aG0[t]    += xq.x*g[0].x   + xq.y*g[1].x   + xq.z*g[2].x   + xq.w*g[3].x;
          aG1[t]    += xq.x*g[0].y   + xq.y*g[1].y   + xq.z*g[2].y   + xq.w*g[3].y;
          a2r[0][t] += xq.x*s2[0].x  + xq.y*s2[1].x  + xq.z*s2[2].x  + xq.w*s2[3].x;
          a2r[1][t] += xq.x*s2[0].y  + xq.y*s2[1].y  + xq.z*s2[2].y  + xq.w*s2[3].y;
          a1r[0][t] += xq.x*u1w[0].x + xq.y*u1w[1].x + xq.z*u1w[2].x + xq.w*u1w[3].x;
          a1r[1][t] += xq.x*u1w[0].y + xq.y*u1w[1].y + xq.z*u1w[2].y + xq.w*u1w[3].y;
          a0r[0][t] += xq.x*v0[0].x  + xq.y*v0[1].x  + xq.z*v0[2].x  + xq.w*v0[3].x;
          a0r[1][t] += xq.x*v0[0].y  + xq.y*v0[1].y  + xq.z*v0[2].y  + xq.w*v0[3].y;
        }
      }
    }
#pragma unroll
    for (int k = 108; k < 111; ++k) {
      float2 gv = *(const float2*)&pG[k * HD];
      float2 sv = *(const float2*)&p2[k * HD];
      float2 uv = *(const float2*)&p1[k * HD];
      float2 vv = *(const float2*)&p0[k * HD];
#pragma unroll
      for (int t = 0; t < 14; ++t) {
        int r = wv + 8 * t;
        if (r < NN0) {
          float xv = xs[r * 112 + k];
          aG0[t]    += xv * gv.x; aG1[t]    += xv * gv.y;
          a2r[0][t] += xv * sv.x; a2r[1][t] += xv * sv.y;
          a1r[0][t] += xv * uv.x; a1r[1][t] += xv * uv.y;
          a0r[0][t] += xv * vv.x; a0r[1][t] += xv * vv.y;
        }
      }
    }
#pragma unroll
    for (int t = 0; t < 14; ++t) {
      int r = wv + 8 * t;
      if (r < NN0) {
        float d1 = dis1[r];
        *(float2*)&bufw[r * 128 + 2 * lane] = make_float2(d1 * aG0[t], d1 * aG1[t]);
      }
    }
  }
  __syncthreads();

  for (int t = 0; t < 14; ++t) {
    int i = wv + 8 * t;
    if (i < NN0) {
      float2 self = *(const float2*)&bufw[i * 128 + 2 * lane];
      float2 ns = nsum2(i);
      float d1 = dis1[i];
      float2 o = make_float2(fmaxf(d1 * (self.x + ns.x), 0.f),
                             fmaxf(d1 * (self.y + ns.y), 0.f));
      *(float2*)&h1b[i * FD + 2 * lane] = o;
    }
  }
  __syncthreads();
#pragma unroll
  for (int t = 0; t < 14; ++t) {
    int r = wv + 8 * t;
    if (r < NN0) {
      float d0r = dis0[r];
      *(float2*)&bufw[r * 128 + 2 * lane] = make_float2(d0r * a2r[0][t], d0r * a2r[1][t]);
    }
  }
  __syncthreads();
  float2 ur[14], cacc[14];
  for (int t = 0; t < 14; ++t) {
    int i = wv + 8 * t;
    if (i < NN0) {
      float2 ns = nsum2(i);
      float sc0 = -dis0[i] * dis0[i];
      ur[t] = make_float2(sc0 * ns.x, sc0 * ns.y);
      cacc[t] = make_float2(-a2r[0][t], -a2r[1][t]);
    } else { ur[t] = make_float2(0.f, 0.f); cacc[t] = make_float2(0.f, 0.f); }
  }
  __syncthreads();
#pragma unroll
  for (int t = 0; t < 14; ++t) {
    int r = wv + 8 * t;
    if (r < NN0) *(float2*)&bufw[r * 128 + 2 * lane] = ur[t];
  }
  __syncthreads();
  for (int t = 0; t < 14; ++t) {
    int i = wv + 8 * t;
    if (i < NN0) {
      float2 ns = nsum2(i);
      float d0i = dis0[i];
      cacc[t].x -= 2.0f * d0i * ns.x;
      cacc[t].y -= 2.0f * d0i * ns.y;
    }
  }
  __syncthreads();
#pragma unroll
  for (int t = 0; t < 14; ++t) {
    int r = wv + 8 * t;
    if (r < NN0) {
      float d0r = dis0[r];
      *(float2*)&bufw[r * 128 + 2 * lane] = make_float2(d0r * a1r[0][t], d0r * a1r[1][t]);
    }
  }
  __syncthreads();
  for (int t = 0; t < 14; ++t) {
    int i = wv + 8 * t;
    if (i < NN0) {
      float2 ns = nsum2(i);
      float d0i = dis0[i];
      float2 o = make_float2(fmaxf(cacc[t].x - d0i * ns.x + a0r[0][t], 0.f),
                             fmaxf(cacc[t].y - d0i * ns.y + a0r[1][t], 0.f));
      *(float2*)&h1b[i * FD + HD + 2 * lane] = o;
    }
  }
}

// ---------------------------------------------------------------------------
// K1b: pool1 scoring/selection only (R17 proven).
// ---------------------------------------------------------------------------
__global__ __launch_bounds__(512) void k_sel(
    const float* __restrict__ h1, const unsigned* __restrict__ abg,
    int* __restrict__ selb, unsigned long long* __restrict__ adjp, int)
{
  extern __shared__ float sm[];
  float* bufw = sm;                                // 112*128 (row 111 = 0)
  unsigned* abits = (unsigned*)(bufw + 14336);     // 448
  float* dinv = (float*)(abits + 448);             // 112
  float* sc   = dinv + 112;                        // 112
  int*   sel  = (int*)(sc + 112);                  // 64

  const int tid = threadIdx.x, lane = tid & 63, wv = tid >> 6;
  const int bl = blockIdx.x;
  const float* h1b = h1 + (size_t)bl * (NN0 * FD);

  for (int q = tid; q < 448; q += 512) abits[q] = abg[(size_t)bl * 448 + q];
  if (tid < 128) bufw[111 * 128 + tid] = 0.0f;
  __syncthreads();
  if (tid < NN0) {
    int d = __popc(abits[tid*4]) + __popc(abits[tid*4+1])
          + __popc(abits[tid*4+2]) + __popc(abits[tid*4+3]);
    dinv[tid] = (d > 0) ? (1.0f / (float)d) : 0.0f;
  }

  auto nsum2 = [&](int i) {
    const unsigned* rb = abits + i * 4;
    unsigned lo0 = (unsigned)__builtin_amdgcn_readfirstlane(rb[0]);
    unsigned hi0 = (unsigned)__builtin_amdgcn_readfirstlane(rb[1]);
    unsigned lo1 = (unsigned)__builtin_amdgcn_readfirstlane(rb[2]);
    unsigned hi1 = (unsigned)__builtin_amdgcn_readfirstlane(rb[3]);
    unsigned long long u0 = ((unsigned long long)hi0 << 32) | (unsigned long long)lo0;
    unsigned long long u1 = ((unsigned long long)hi1 << 32) | (unsigned long long)lo1;
    float2 s0 = {0,0}, s1 = {0,0}, s2 = {0,0}, s3 = {0,0};
    while (u0 | u1) {
      int j0 = u0 ? (int)__builtin_ctzll(u0) : 111; u0 &= u0 - 1;
      int j1 = u0 ? (int)__builtin_ctzll(u0) : 111; u0 &= u0 - 1;
      int j2 = u1 ? (int)(64 + __builtin_ctzll(u1)) : 111; u1 &= u1 - 1;
      int j3 = u1 ? (int)(64 + __builtin_ctzll(u1)) : 111; u1 &= u1 - 1;
      float2 p0 = *(const float2*)&bufw[j0 * 128 + 2 * lane];
      float2 p1 = *(const float2*)&bufw[j1 * 128 + 2 * lane];
      float2 p2 = *(const float2*)&bufw[j2 * 128 + 2 * lane];
      float2 p3 = *(const float2*)&bufw[j3 * 128 + 2 * lane];
      s0.x += p0.x; s0.y += p0.y; s1.x += p1.x; s1.y += p1.y;
      s2.x += p2.x; s2.y += p2.y; s3.x += p3.x; s3.y += p3.y;
    }
    return make_float2((s0.x + s1.x) + (s2.x + s3.x),
                       (s0.y + s1.y) + (s2.y + s3.y));
  };

#pragma unroll
  for (int t = 0; t < 14; ++t) {
    int r = wv + 8 * t;
    if (r < NN0)
      *(float2*)&bufw[r * 128 + 2 * lane] = *(const float2*)&h1b[r * FD + 2 * lane];
  }
  __syncthreads();
  float sA[14];
  for (int t = 0; t < 14; ++t) {
    int i = wv + 8 * t;
    if (i < NN0) {
      float2 self = *(const float2*)&bufw[i * 128 + 2 * lane];
      float2 nb = nsum2(i);
      float di = dinv[i];
      sA[t] = fabsf(self.x - di * nb.x) + fabsf(self.y - di * nb.y);
    } else sA[t] = 0.f;
  }
  __syncthreads();
#pragma unroll
  for (int t = 0; t < 14; ++t) {
    int r = wv + 8 * t;
    if (r < NN0)
      *(float2*)&bufw[r * 128 + 2 * lane] = *(const float2*)&h1b[r * FD + HD + 2 * lane];
  }
  __syncthreads();
  for (int t = 0; t < 14; ++t) {
    int i = wv + 8 * t;
    if (i < NN0) {
      float2 self = *(const float2*)&bufw[i * 128 + 2 * lane];
      float2 nb = nsum2(i);
      float di = dinv[i];
      float s = sA[t] + fabsf(self.x - di * nb.x) + fabsf(self.y - di * nb.y);
      for (int off = 32; off; off >>= 1) s += __shfl_xor(s, off);
      if (lane == 0) sc[i] = s;
    }
  }
  __syncthreads();
  if (tid < NN0) {
    float my = sc[tid];
    int cnt = 0;
    for (int j = 0; j < NN0; ++j) {
      float sj = sc[j];
      cnt += (sj > my) || (sj == my && j < tid);
    }
    if (cnt < NN1) sel[cnt] = tid;
  }
  __syncthreads();
  for (int r = wv; r < NN1; r += 8) {
    int i = sel[r];
    int j2 = (lane < NN1) ? sel[lane] : 0;
    bool bit = (lane < NN1) && ((abits[i * 4 + (j2 >> 5)] >> (j2 & 31)) & 1);
    unsigned long long m = __ballot(bit);
    if (lane == 0) adjp[(size_t)bl * NN1 + r] = m;
  }
  if (tid < NN1) selb[(size_t)bl * NN1 + tid] = sel[tid];
}

// ---------------------------------------------------------------------------
// K2: stage-2 conv FUSED with pool2 + x1/x2 readouts (R16 proven).
// ---------------------------------------------------------------------------
__global__ __launch_bounds__(512, 2) void k_stage2(
    const float* __restrict__ h1, const int* __restrict__ selb,
    const unsigned long long* __restrict__ adjp,
    const float* __restrict__ wg, const float* __restrict__ wsp,
    float* __restrict__ zbuf)
{
  extern __shared__ float sm[];
  float* hs   = sm;                                // 57*256 (row 56 = 0)
  float* bufw = hs + 14592;                        // 57*128 (row 56 = 0)
  unsigned long long* rowm = (unsigned long long*)(bufw + 7296); // 56 u64
  float* dis0 = (float*)(rowm + 56);               // 64
  float* dis1 = dis0 + 64;                         // 64
  float* dinv = dis1 + 64;                         // 64
  float* sc   = dinv + 64;                         // 64
  int* sel2   = (int*)(sc + 64);                   // 32
  int* seli   = sel2 + 32;                         // 64

  const int tid = threadIdx.x, lane = tid & 63, wv = tid >> 6;
  const int bl = blockIdx.x;
  const float* h1b = h1 + (size_t)bl * (NN0 * FD);
  float* zb = zbuf + (size_t)bl * 8192;

  if (tid < NN1) seli[tid] = selb[(size_t)bl * NN1 + tid];
  if (tid < 128) bufw[56 * 128 + tid] = 0.0f;
  if (tid < 256) hs[56 * 256 + tid] = 0.0f;
  if (tid < NN1) {
    unsigned long long m = adjp[(size_t)bl * NN1 + tid];
    rowm[tid] = m;
    int d = __popcll(m);
    dis0[tid] = (d > 0) ? (1.0f / sqrtf((float)d)) : 0.0f;
    dis1[tid] = 1.0f / sqrtf((float)(d + 1));
    dinv[tid] = (d > 0) ? (1.0f / (float)d) : 0.0f;
  }
  __syncthreads();
  for (int q = tid; q < NN1 * 64; q += 512) {
    int row = q >> 6, c = q & 63;
    ((float4*)hs)[row * 64 + c] =
        ((const float4*)(h1b + (size_t)seli[row] * FD))[c];
  }
  __syncthreads();
  if (tid < FD) {
    float mx = -3.402823466e38f, sm2 = 0.0f;
    for (int r = 0; r < NN1; ++r) {
      float v = hs[r * 256 + tid];
      mx = fmaxf(mx, v); sm2 += v;
    }
    zb[7168 + tid] = mx;
    zb[7424 + tid] = sm2 / 56.0f;
  }

  auto nsum2 = [&](int i) {
    unsigned long long m = rowm[i];
    unsigned lo = (unsigned)__builtin_amdgcn_readfirstlane((unsigned)m);
    unsigned hi = (unsigned)__builtin_amdgcn_readfirstlane((unsigned)(m >> 32));
    unsigned long long u = ((unsigned long long)hi << 32) | (unsigned long long)lo;
    float2 s0 = {0,0}, s1 = {0,0}, s2 = {0,0}, s3 = {0,0};
    while (u) {
      int j0 = (int)__builtin_ctzll(u); u &= u - 1;
      int j1 = u ? (int)__builtin_ctzll(u) : 56; u &= u - 1;
      int j2 = u ? (int)__builtin_ctzll(u) : 56; u &= u - 1;
      int j3 = u ? (int)__builtin_ctzll(u) : 56; u &= u - 1;
      float2 p0 = *(const float2*)&bufw[j0 * 128 + 2 * lane];
      float2 p1 = *(const float2*)&bufw[j1 * 128 + 2 * lane];
      float2 p2 = *(const float2*)&bufw[j2 * 128 + 2 * lane];
      float2 p3 = *(const float2*)&bufw[j3 * 128 + 2 * lane];
      s0.x += p0.x; s0.y += p0.y; s1.x += p1.x; s1.y += p1.y;
      s2.x += p2.x; s2.y += p2.y; s3.x += p3.x; s3.y += p3.y;
    }
    return make_float2((s0.x + s1.x) + (s2.x + s3.x),
                       (s0.y + s1.y) + (s2.y + s3.y));
  };
  auto nsum_hs = [&](int i, int base) {
    unsigned long long m = rowm[i];
    unsigned lo = (unsigned)__builtin_amdgcn_readfirstlane((unsigned)m);
    unsigned hi = (unsigned)__builtin_amdgcn_readfirstlane((unsigned)(m >> 32));
    unsigned long long u = ((unsigned long long)hi << 32) | (unsigned long long)lo;
    float2 s0 = {0,0}, s1 = {0,0}, s2 = {0,0}, s3 = {0,0};
    while (u) {
      int j0 = (int)__builtin_ctzll(u); u &= u - 1;
      int j1 = u ? (int)__builtin_ctzll(u) : 56; u &= u - 1;
      int j2 = u ? (int)__builtin_ctzll(u) : 56; u &= u - 1;
      int j3 = u ? (int)__builtin_ctzll(u) : 56; u &= u - 1;
      float2 p0 = *(const float2*)&hs[j0 * 256 + base + 2 * lane];
      float2 p1 = *(const float2*)&hs[j1 * 256 + base + 2 * lane];
      float2 p2 = *(const float2*)&hs[j2 * 256 + base + 2 * lane];
      float2 p3 = *(const float2*)&hs[j3 * 256 + base + 2 * lane];
      s0.x += p0.x; s0.y += p0.y; s1.x += p1.x; s1.y += p1.y;
      s2.x += p2.x; s2.y += p2.y; s3.x += p3.x; s3.y += p3.y;
    }
    return make_float2((s0.x + s1.x) + (s2.x + s3.x),
                       (s0.y + s1.y) + (s2.y + s3.y));
  };

  float aG0[7], aG1[7];
  float a2r[2][7], a1r[2][7], a0r[2][7];
#pragma unroll
  for (int t = 0; t < 7; ++t) {
    aG0[t] = 0.f; aG1[t] = 0.f;
    a2r[0][t] = 0.f; a2r[1][t] = 0.f;
    a1r[0][t] = 0.f; a1r[1][t] = 0.f;
    a0r[0][t] = 0.f; a0r[1][t] = 0.f;
  }
  {
    const float* pG = wg  + 2 * lane;
    const float* p2 = wsp + 2 * (FD * HD) + 2 * lane;
    const float* p1 = wsp + 1 * (FD * HD) + 2 * lane;
    const float* p0 = wsp + 2 * lane;
    for (int kq = 0; kq < 64; ++kq) {
      int k0 = kq * 4;
      float2 g[4], s2[4], u1w[4], v0[4];
#pragma unroll
      for (int j = 0; j < 4; ++j) {
        g[j]   = *(const float2*)&pG[(k0 + j) * HD];
        s2[j]  = *(const float2*)&p2[(k0 + j) * HD];
        u1w[j] = *(const float2*)&p1[(k0 + j) * HD];
        v0[j]  = *(const float2*)&p0[(k0 + j) * HD];
      }
#pragma unroll
      for (int t = 0; t < 7; ++t) {
        int r = wv + 8 * t;
        float4 xq = *(const float4*)(hs + r * 256 + k0);
        aG0[t]    += xq.x*g[0].x   + xq.y*g[1].x   + xq.z*g[2].x   + xq.w*g[3].x;
        aG1[t]    += xq.x*g[0].y   + xq.y*g[1].y   + xq.z*g[2].y   + xq.w*g[3].y;
        a2r[0][t] += xq.x*s2[0].x  + xq.y*s2[1].x  + xq.z*s2[2].x  + xq.w*s2[3].x;
        a2r[1][t] += xq.x*s2[0].y  + xq.y*s2[1].y  + xq.z*s2[2].y  + xq.w*s2[3].y;
        a1r[0][t] += xq.x*u1w[0].x + xq.y*u1w[1].x + xq.z*u1w[2].x + xq.w*u1w[3].x;
        a1r[1][t] += xq.x*u1w[0].y + xq.y*u1w[1].y + xq.z*u1w[2].y + xq.w*u1w[3].y;
        a0r[0][t] += xq.x*v0[0].x  + xq.y*v0[1].x  + xq.z*v0[2].x  + xq.w*v0[3].x;
        a0r[1][t] += xq.x*v0[0].y  + xq.y*v0[1].y  + xq.z*v0[2].y  + xq.w*v0[3].y;
      }
    }
#pragma unroll
    for (int t = 0; t < 7; ++t) {
      int r = wv + 8 * t;
      float d1 = dis1[r];
      *(float2*)&bufw[r * 128 + 2 * lane] = make_float2(d1 * aG0[t], d1 * aG1[t]);
    }
  }
  __syncthreads();
  float2 ho[7];
#pragma unroll
  for (int t = 0; t < 7; ++t) {
    int i = wv + 8 * t;
    float2 self = *(const float2*)&bufw[i * 128 + 2 * lane];
    float2 ns = nsum2(i);
    float d1 = dis1[i];
    float2 o = make_float2(fmaxf(d1 * (self.x + ns.x), 0.f),
                           fmaxf(d1 * (self.y + ns.y), 0.f));
    *(float2*)&hs[i * 256 + 2 * lane] = o;
    ho[t] = o;
  }
  __syncthreads();
  float sA[7];
#pragma unroll
  for (int t = 0; t < 7; ++t) {
    int i = wv + 8 * t;
    float2 nb = nsum_hs(i, 0);
    float di = dinv[i];
    sA[t] = fabsf(ho[t].x - di * nb.x) + fabsf(ho[t].y - di * nb.y);
  }
#pragma unroll
  for (int t = 0; t < 7; ++t) {
    int r = wv + 8 * t;
    float d0r = dis0[r];
    *(float2*)&bufw[r * 128 + 2 * lane] = make_float2(d0r * a2r[0][t], d0r * a2r[1][t]);
  }
  __syncthreads();
  float2 ur[7], cacc[7];
#pragma unroll
  for (int t = 0; t < 7; ++t) {
    int i = wv + 8 * t;
    float2 ns = nsum2(i);
    float sc0 = -dis0[i] * dis0[i];
    ur[t] = make_float2(sc0 * ns.x, sc0 * ns.y);
    cacc[t] = make_float2(-a2r[0][t], -a2r[1][t]);
  }
  __syncthreads();
#pragma unroll
  for (int t = 0; t < 7; ++t) {
    int r = wv + 8 * t;
    *(float2*)&bufw[r * 128 + 2 * lane] = ur[t];
  }
  __syncthreads();
#pragma unroll
  for (int t = 0; t < 7; ++t) {
    int i = wv + 8 * t;
    float2 ns = nsum2(i);
    float d0i = dis0[i];
    cacc[t].x -= 2.0f * d0i * ns.x;
    cacc[t].y -= 2.0f * d0i * ns.y;
  }
  __syncthreads();
#pragma unroll
  for (int t = 0; t < 7; ++t) {
    int r = wv + 8 * t;
    float d0r = dis0[r];
    *(float2*)&bufw[r * 128 + 2 * lane] = make_float2(d0r * a1r[0][t], d0r * a1r[1][t]);
  }
  __syncthreads();
#pragma unroll
  for (int t = 0; t < 7; ++t) {
    int i = wv + 8 * t;
    float2 ns = nsum2(i);
    float d0i = dis0[i];
    float2 o = make_float2(fmaxf(cacc[t].x - d0i * ns.x + a0r[0][t], 0.f),
                           fmaxf(cacc[t].y - d0i * ns.y + a0r[1][t], 0.f));
    *(float2*)&hs[i * 256 + 128 + 2 * lane] = o;
    cacc[t] = o;
  }
  __syncthreads();
#pragma unroll
  for (int t = 0; t < 7; ++t) {
    int i = wv + 8 * t;
    float2 nb = nsum_hs(i, 128);
    float di = dinv[i];
    float s = sA[t] + fabsf(cacc[t].x - di * nb.x) + fabsf(cacc[t].y - di * nb.y);
    for (int off = 32; off; off >>= 1) s += __shfl_xor(s, off);
    if (lane == 0) sc[i] = s;
  }
  __syncthreads();
  if (tid < NN1) {
    float my = sc[tid];
    int cnt = 0;
    for (int j = 0; j < NN1; ++j) {
      float sj = sc[j];
      cnt += (sj > my) || (sj == my && j < tid);
    }
    if (cnt < NN2) sel2[cnt] = tid;
  }
  __syncthreads();
  for (int r = wv; r < NN2; r += 8) {
    const float* hr = hs + sel2[r] * 256 + lane;
    float* dst = zb + r * 256 + lane;
    dst[0] = hr[0]; dst[64] = hr[64]; dst[128] = hr[128]; dst[192] = hr[192];
  }
  if (tid < FD) {
    float mx = -3.402823466e38f, sm2 = 0.0f;
    for (int r = 0; r < NN2; ++r) {
      float v = hs[sel2[r] * 256 + tid];
      mx = fmaxf(mx, v); sm2 += v;
    }
    zb[7680 + tid] = mx;
    zb[7936 + tid] = sm2 / 28.0f;
  }
}

// ---------------------------------------------------------------------------
// K5a: lin1 split-K partial. grid (G/8, 4): blockIdx.y = K-quarter (2048).
// ---------------------------------------------------------------------------
__global__ __launch_bounds__(512) void k_lin1p(
    const float* __restrict__ zbuf, const float* __restrict__ w,
    float* __restrict__ part, int G)
{
  __shared__ float smem[8576];           // wt: 32*260=8320 | zt: 32*8=256
  float* wt = smem;
  float* zt = smem + 8320;

  const int tid = threadIdx.x;
  const int col = tid & 63;
  const int ksub = tid >> 6;             // 0..7
  const int g0 = blockIdx.x * 8;
  const int kq4 = blockIdx.y;            // K-quarter
  const int kbase = kq4 * 2048;
  const int gz = tid >> 5, kz = tid & 31;

  float acc[8][4];
#pragma unroll
  for (int g = 0; g < 8; ++g)
#pragma unroll
    for (int c = 0; c < 4; ++c) acc[g][c] = 0.f;

  const float* wbase = w + (size_t)(kbase + ksub) * 256 + col * 4;
  const float* zbase = zbuf + (size_t)(g0 + gz) * 8192 + kbase + kz;

  float4 wr4[4]; float zr1 = 0.f;
#pragma unroll
  for (int q = 0; q < 4; ++q)
    wr4[q] = *(const float4*)(wbase + (size_t)(8 * q) * 256);
  if (tid < 256) zr1 = zbase[0];
#pragma unroll
  for (int q = 0; q < 4; ++q)
    *(float4*)&wt[(ksub + 8 * q) * 260 + col * 4] = wr4[q];
  if (tid < 256) zt[kz * 8 + gz] = zr1;
  __syncthreads();

  for (int it = 0; it < 64; ++it) {
    if (it + 1 < 64) {
      const float* wn = wbase + (size_t)(it + 1) * 32 * 256;
#pragma unroll
      for (int q = 0; q < 4; ++q)
        wr4[q] = *(const float4*)(wn + (size_t)(8 * q) * 256);
      if (tid < 256) zr1 = zbase[(it + 1) * 32];
    }
#pragma unroll
    for (int kk = 0; kk < 4; ++kk) {
      int k = ksub * 4 + kk;
      float4 za = *(const float4*)&zt[k * 8];
      float4 zb = *(const float4*)&zt[k * 8 + 4];
      float4 wv = *(const float4*)&wt[k * 260 + col * 4];
      acc[0][0] += za.x * wv.x; acc[0][1] += za.x * wv.y; acc[0][2] += za.x * wv.z; acc[0][3] += za.x * wv.w;
      acc[1][0] += za.y * wv.x; acc[1][1] += za.y * wv.y; acc[1][2] += za.y * wv.z; acc[1][3] += za.y * wv.w;
      acc[2][0] += za.z * wv.x; acc[2][1] += za.z * wv.y; acc[2][2] += za.z * wv.z; acc[2][3] += za.z * wv.w;
      acc[3][0] += za.w * wv.x; acc[3][1] += za.w * wv.y; acc[3][2] += za.w * wv.z; acc[3][3] += za.w * wv.w;
      acc[4][0] += zb.x * wv.x; acc[4][1] += zb.x * wv.y; acc[4][2] += zb.x * wv.z; acc[4][3] += zb.x * wv.w;
      acc[5][0] += zb.y * wv.x; acc[5][1] += zb.y * wv.y; acc[5][2] += zb.y * wv.z; acc[5][3] += zb.y * wv.w;
      acc[6][0] += zb.z * wv.x; acc[6][1] += zb.z * wv.y; acc[6][2] += zb.z * wv.z; acc[6][3] += zb.z * wv.w;
      acc[7][0] += zb.w * wv.x; acc[7][1] += zb.w * wv.y; acc[7][2] += zb.w * wv.z; acc[7][3] += zb.w * wv.w;
    }
    __syncthreads();
    if (it + 1 < 64) {
#pragma unroll
      for (int q = 0; q < 4; ++q)
        *(float4*)&wt[(ksub + 8 * q) * 260 + col * 4] = wr4[q];
      if (tid < 256) zt[kz * 8 + gz] = zr1;
      __syncthreads();
    }
  }

  float* red = smem;
  for (int half = 4; half >= 1; half >>= 1) {
    if (ksub >= half && ksub < 2 * half) {
      float* dst = red + ((ksub - half) * 64 + col) * 33;
#pragma unroll
      for (int g = 0; g < 8; ++g)
#pragma unroll
        for (int c = 0; c < 4; ++c) dst[g * 4 + c] = acc[g][c];
    }
    __syncthreads();
    if (ksub < half) {
      const float* src = red + (ksub * 64 + col) * 33;
#pragma unroll
      for (int g = 0; g < 8; ++g)
#pragma unroll
        for (int c = 0; c < 4; ++c) acc[g][c] += src[g * 4 + c];
    }
    __syncthreads();
  }
  if (ksub == 0) {
    float* pb = part + ((size_t)kq4 * G + g0) * 256;
#pragma unroll
    for (int g = 0; g < 8; ++g) {
      float4 v = make_float4(acc[g][0], acc[g][1], acc[g][2], acc[g][3]);
      *(float4*)&pb[(size_t)g * 256 + col * 4] = v;
    }
  }
}

// ---------------------------------------------------------------------------
// K5b: reduce 4 K-quarter partials + bias + relu -> fbuf. Fixed order.
// ---------------------------------------------------------------------------
__global__ __launch_bounds__(256) void k_lin1r(
    const float* __restrict__ part, const float* __restrict__ bias,
    float* __restrict__ fbuf, int G)
{
  int idx = blockIdx.x * 256 + threadIdx.x;   // float4 index over G*64
  int c4 = idx & 63, g = idx >> 6;
  size_t stride = (size_t)G * 256;
  const float* p = part + (size_t)g * 256 + c4 * 4;
  float4 s = *(const float4*)p;
#pragma unroll
  for (int q = 1; q < 4; ++q) {
    float4 v = *(const float4*)(p + (size_t)q * stride);
    s.x += v.x; s.y += v.y; s.z += v.z; s.w += v.w;
  }
  float4 bv = *(const float4*)(bias + c4 * 4);
  s.x = fmaxf(s.x + bv.x, 0.f); s.y = fmaxf(s.y + bv.y, 0.f);
  s.z = fmaxf(s.z + bv.z, 0.f); s.w = fmaxf(s.w + bv.w, 0.f);
  *(float4*)(fbuf + (size_t)g * 256 + c4 * 4) = s;
}

// ---------------------------------------------------------------------------
// K6: features = relu(f @ lin2_w + b2); x_lo = softmax(features)
// ---------------------------------------------------------------------------
__global__ __launch_bounds__(128) void k_head(
    const float* __restrict__ fbuf, const float* __restrict__ w2,
    const float* __restrict__ b2, float* __restrict__ out, int b0)
{
  __shared__ __align__(16) float fs[256];
  __shared__ float red[2];
  const int tid = threadIdx.x, lane = tid & 63, wv = tid >> 6;
  const int bl = blockIdx.x, b = b0 + bl;
  for (int i = tid; i < 256; i += 128) fs[i] = fbuf[(size_t)bl * 256 + i];
  __syncthreads();
  float acc = b2[tid];
  for (int k = 0; k < 256; k += 4) {
    float4 fq = *(const float4*)(fs + k);
    acc += fq.x * w2[(k + 0) * 128 + tid] + fq.y * w2[(k + 1) * 128 + tid]
         + fq.z * w2[(k + 2) * 128 + tid] + fq.w * w2[(k + 3) * 128 + tid];
  }
  float feat = fmaxf(acc, 0.0f);
  out[(size_t)(NB * 128) + (size_t)b * 128 + tid] = feat;
  float m = feat;
  for (int off = 32; off; off >>= 1) m = fmaxf(m, __shfl_xor(m, off));
  if (lane == 0) red[wv] = m;
  __syncthreads();
  m = fmaxf(red[0], red[1]);
  float e = expf(feat - m);
  float s = e;
  for (int off = 32; off; off >>= 1) s += __shfl_xor(s, off);
  __syncthreads();
  if (lane == 0) red[wv] = s;
  __syncthreads();
  s = red[0] + red[1];
  out[(size_t)b * 128 + tid] = e / s;
}

// ---------------------------------------------------------------------------
extern "C" void kernel_launch(void* const* d_in, const int* in_sizes, int n_in,
                              void* d_out, int out_size, void* d_ws, size_t ws_size,
                              hipStream_t stream) {
  const float* x    = (const float*)d_in[0];
  const float* adj  = (const float*)d_in[1];
  const float* wg1  = (const float*)d_in[2];
  const float* wsp1 = (const float*)d_in[3];
  const float* wg2  = (const float*)d_in[4];
  const float* wsp2 = (const float*)d_in[5];
  const float* l1w  = (const float*)d_in[6];
  const float* l1b  = (const float*)d_in[7];
  const float* l2w  = (const float*)d_in[8];
  const float* l2b  = (const float*)d_in[9];
  float* out = (float*)d_out;

  auto al = [](size_t v) { return (v + 255) & ~(size_t)255; };
  size_t oh1, oabg, oselb, oadjp, oz, opart, of;
  auto plan = [&](int g) -> size_t {
    size_t o = 0;
    oh1 = o;   o += al((size_t)g * NN0 * FD * 4);
    oabg = o;  o += al((size_t)g * 448 * 4);
    oselb = o; o += al((size_t)g * NN1 * 4);
    oadjp = o; o += al((size_t)g * NN1 * 8);
    oz = o;    o += al((size_t)g * 8192 * 4);
    opart = o; o += al((size_t)g * 256 * 4 * 4);
    of = o;    o += al((size_t)g * FD * 4);
    return o;
  };
  // G=1024 (best measured config, R20): ~3.09ms
  int G = 1024;
  while (G > 64 && plan(G) > ws_size) G >>= 1;
  if (plan(G) > ws_size) return;

  char* wsb = (char*)d_ws;
  float* h1  = (float*)(wsb + oh1);
  unsigned* abg = (unsigned*)(wsb + oabg);
  int* selb  = (int*)(wsb + oselb);
  unsigned long long* adjp = (unsigned long long*)(wsb + oadjp);
  float* zbuf = (float*)(wsb + oz);
  float* part = (float*)(wsb + opart);
  float* fbuf = (float*)(wsb + of);

  const size_t LDS1 = (size_t)(12432 + 14336 + 448 + 112 + 112) * 4;            // 109,760
  const size_t LDSS = (size_t)(14336 + 448 + 112 + 112 + 64) * 4;               // 60,288
  const size_t LDS2 = (size_t)(14592 + 7296 + 112 + 64 + 64 + 64 + 64 + 32 + 64) * 4; // 89,408

  for (int b0 = 0; b0 < NB; b0 += G) {
    k_stage1<<<G, 512, LDS1, stream>>>(x, adj, wg1, wsp1, h1, abg, b0);
    k_sel<<<G, 512, LDSS, stream>>>(h1, abg, selb, adjp, b0);
    k_stage2<<<G, 512, LDS2, stream>>>(h1, selb, adjp, wg2, wsp2, zbuf);
    k_lin1p<<<dim3(G / 8, 4), 512, 0, stream>>>(zbuf, l1w, part, G);
    k_lin1r<<<G / 4, 256, 0, stream>>>(part, l1b, fbuf, G);
    k_head<<<G, 128, 0, stream>>>(fbuf, l2w, l2b, out, b0);
  }
}